// Round 3
// baseline (274.122 us; speedup 1.0000x reference)
//
#include <hip/hip_runtime.h>

// VectorQuantizer MI355X (gfx950) — round 3
// R2 post-mortem: 60% stall cycles (MfmaUtil 15 + VALU 26), 83us launch/prep overhead.
// Changes: (1) register double-buffer prefetch of codebook fragments in the t-loop,
//          (2) merge prep1+prep2 into one kernel, (3) fold final loss write into
//              vq_main via device-scope completion counter -> 2 launches total.

#define NVEC 262144
#define DDIM 64
#define KCB  512
#define TIE_TH 1e-3f
#define NBLOCKS (NVEC / 256)

// ws layout (4-byte units)
#define WS_LOSS  0
#define WS_COUNT 1
#define WS_CNORM 64                      // 512 floats
#define WS_ET    1024                    // 512*64 floats (code-major codebook)
#define WS_EH    (WS_ET + KCB * DDIM)    // 32 tiles * 2 chunks * 64 lanes * 4 (uint4 units below)
#define WS_EL    (WS_EH + 32 * 2 * 64 * 4)
#define WS_END   (WS_EL + 32 * 2 * 64 * 4)

typedef __attribute__((ext_vector_type(8))) short bf16x8;
typedef __attribute__((ext_vector_type(4))) float f32x4;

static __device__ __forceinline__ unsigned short f2bf_rne(float f) {
    unsigned u = __float_as_uint(f);
    unsigned r = (u + 0x7FFFu + ((u >> 16) & 1u)) >> 16;
    return (unsigned short)r;
}
static __device__ __forceinline__ float bf2f(unsigned short h) {
    return __uint_as_float(((unsigned)h) << 16);
}

// ---------------- merged prep: 9 blocks x 512 ----------------
// blocks 0..7 : build MFMA A-fragments (hi/lo bf16) for the codebook
// block  8    : et (code-major fp32), cnorm, zero loss+counter
__global__ __launch_bounds__(512) void vq_prep(const float* __restrict__ emb,
                                               float* __restrict__ wsf) {
    if (blockIdx.x == 8) {
        int k = threadIdx.x;
        float s = 0.f;
        float* et = wsf + WS_ET;
        #pragma unroll
        for (int d = 0; d < DDIM; ++d) {
            float e = emb[d * KCB + k];
            s += e * e;
            et[k * DDIM + d] = e;
        }
        wsf[WS_CNORM + k] = s;
        if (k == 0) {
            wsf[WS_LOSS] = 0.f;
            ((unsigned*)wsf)[WS_COUNT] = 0u;
        }
        return;
    }
    int tid = blockIdx.x * 512 + threadIdx.x;   // 0..4095
    int l = tid & 63;
    int c = (tid >> 6) & 1;
    int t = tid >> 7;
    int m = t * 16 + (l & 15);
    int dbase = c * 32 + ((l >> 4) & 3) * 8;
    unsigned hh[4], ll[4];
    #pragma unroll
    for (int j2 = 0; j2 < 4; ++j2) {
        float f0 = emb[(dbase + 2 * j2 + 0) * KCB + m];
        float f1 = emb[(dbase + 2 * j2 + 1) * KCB + m];
        unsigned short h0 = f2bf_rne(f0), h1 = f2bf_rne(f1);
        unsigned short l0 = f2bf_rne(f0 - bf2f(h0)), l1 = f2bf_rne(f1 - bf2f(h1));
        hh[j2] = (unsigned)h0 | ((unsigned)h1 << 16);
        ll[j2] = (unsigned)l0 | ((unsigned)l1 << 16);
    }
    uint4* ehp = (uint4*)(wsf + WS_EH);
    uint4* elp = (uint4*)(wsf + WS_EL);
    ehp[tid] = make_uint4(hh[0], hh[1], hh[2], hh[3]);
    elp[tid] = make_uint4(ll[0], ll[1], ll[2], ll[3]);
}

// ---------------- main: one wave = 64 vectors vs all 512 codes ----------------
__global__ __launch_bounds__(256) void vq_main_mfma(const float* __restrict__ x,
                                                    float* __restrict__ wsf,
                                                    float* __restrict__ out) {
    const int lane = threadIdx.x & 63;
    const int quad = lane >> 4;
    const int nbase = (blockIdx.x * 4 + (threadIdx.x >> 6)) * 64;

    const float* __restrict__ cnorm = wsf + WS_CNORM;
    const float* __restrict__ et    = wsf + WS_ET;
    const bf16x8* __restrict__ ehp  = (const bf16x8*)(wsf + WS_EH);
    const bf16x8* __restrict__ elp  = (const bf16x8*)(wsf + WS_EL);
    float* loss_accum = wsf + WS_LOSS;
    unsigned* counter = (unsigned*)wsf + WS_COUNT;

    // ---- load x tile, build B-fragments (hi/lo), accumulate ||x||^2 ----
    bf16x8 xh[4][2], xl[4][2];
    float xnorm[4];
    #pragma unroll
    for (int j = 0; j < 4; ++j) {
        float s = 0.f;
        #pragma unroll
        for (int c = 0; c < 2; ++c) {
            const float* xrow = x + (size_t)(nbase + j * 16 + (lane & 15)) * DDIM
                                  + c * 32 + quad * 8;
            float4 xa = *(const float4*)xrow;
            float4 xb = *(const float4*)(xrow + 4);
            s += xa.x * xa.x + xa.y * xa.y + xa.z * xa.z + xa.w * xa.w;
            s += xb.x * xb.x + xb.y * xb.y + xb.z * xb.z + xb.w * xb.w;
            float f[8] = {xa.x, xa.y, xa.z, xa.w, xb.x, xb.y, xb.z, xb.w};
            union { bf16x8 v; unsigned short u[8]; } H, L;
            #pragma unroll
            for (int e = 0; e < 8; ++e) {
                unsigned short h = f2bf_rne(f[e]);
                H.u[e] = h;
                L.u[e] = f2bf_rne(f[e] - bf2f(h));
            }
            xh[j][c] = H.v;
            xl[j][c] = L.v;
        }
        s += __shfl_xor(s, 16);
        s += __shfl_xor(s, 32);
        xnorm[j] = s;
    }

    // ---- argmin over 32 code-tiles, register double-buffer prefetch ----
    float best[4], second[4];
    int bestv[4];
    #pragma unroll
    for (int j = 0; j < 4; ++j) { best[j] = 3.4e38f; second[j] = 3.4e38f; bestv[j] = 0; }

    bf16x8 ceh0 = ehp[lane], ceh1 = ehp[64 + lane];
    bf16x8 cel0 = elp[lane], cel1 = elp[64 + lane];
    float4 ccn = *(const float4*)(cnorm + quad * 4);

    for (int t = 0; t < 32; ++t) {
        const int tn = (t + 1) & 31;   // wraps to 0 on last iter (valid, unused result)
        bf16x8 neh0 = ehp[(tn * 2 + 0) * 64 + lane];
        bf16x8 neh1 = ehp[(tn * 2 + 1) * 64 + lane];
        bf16x8 nel0 = elp[(tn * 2 + 0) * 64 + lane];
        bf16x8 nel1 = elp[(tn * 2 + 1) * 64 + lane];
        float4 ncn = *(const float4*)(cnorm + tn * 16 + quad * 4);

        const int kb = t * 16;
        #pragma unroll
        for (int j = 0; j < 4; ++j) {
            f32x4 acc = {0.f, 0.f, 0.f, 0.f};
            acc = __builtin_amdgcn_mfma_f32_16x16x32_bf16(ceh0, xh[j][0], acc, 0, 0, 0);
            acc = __builtin_amdgcn_mfma_f32_16x16x32_bf16(ceh1, xh[j][1], acc, 0, 0, 0);
            acc = __builtin_amdgcn_mfma_f32_16x16x32_bf16(cel0, xh[j][0], acc, 0, 0, 0);
            acc = __builtin_amdgcn_mfma_f32_16x16x32_bf16(cel1, xh[j][1], acc, 0, 0, 0);
            acc = __builtin_amdgcn_mfma_f32_16x16x32_bf16(ceh0, xl[j][0], acc, 0, 0, 0);
            acc = __builtin_amdgcn_mfma_f32_16x16x32_bf16(ceh1, xl[j][1], acc, 0, 0, 0);
            float cns[4] = {ccn.x, ccn.y, ccn.z, ccn.w};
            #pragma unroll
            for (int r = 0; r < 4; ++r) {
                float dist = __builtin_fmaf(-2.f, acc[r], cns[r]);
                bool lt = dist < best[j];
                second[j] = fminf(second[j], fmaxf(dist, best[j]));
                bestv[j] = lt ? (kb + r) : bestv[j];
                best[j] = fminf(best[j], dist);
            }
        }
        ceh0 = neh0; ceh1 = neh1; cel0 = nel0; cel1 = nel1; ccn = ncn;
    }

    // ---- reduce across the 4 quads ----
    int bk[4];
    #pragma unroll
    for (int j = 0; j < 4; ++j) bk[j] = bestv[j] + quad * 4;
    #pragma unroll
    for (int j = 0; j < 4; ++j) {
        #pragma unroll
        for (int m = 16; m <= 32; m <<= 1) {
            float ob = __shfl_xor(best[j], m);
            float os = __shfl_xor(second[j], m);
            int   ok = __shfl_xor(bk[j], m);
            float nb = fminf(best[j], ob);
            float ns = fminf(fminf(second[j], os), fmaxf(best[j], ob));
            bool take = (ob < best[j]) || (ob == best[j] && ok < bk[j]);
            bk[j] = take ? ok : bk[j];
            best[j] = nb;
            second[j] = ns;
        }
    }

    // ---- near-tie: whole-wave cooperative exact fp64 rescan (rare) ----
    #pragma unroll
    for (int j = 0; j < 4; ++j) {
        unsigned long long need = __ballot(second[j] - best[j] < TIE_TH) & 0xFFFFULL;
        while (need) {
            int nl = __ffsll(need) - 1;
            need &= need - 1;
            const float* xr = x + (size_t)(nbase + j * 16 + nl) * DDIM;
            double dmin = 1e300;
            int kmin = 0;
            #pragma unroll
            for (int i = 0; i < 8; ++i) {
                int k = lane * 8 + i;
                const float* er = et + k * DDIM;
                double s = 0.0;
                for (int d4 = 0; d4 < 16; ++d4) {
                    float4 xv = *(const float4*)(xr + d4 * 4);
                    float4 ev = *(const float4*)(er + d4 * 4);
                    double a = (double)xv.x - (double)ev.x; s += a * a;
                    double b = (double)xv.y - (double)ev.y; s += b * b;
                    double c = (double)xv.z - (double)ev.z; s += c * c;
                    double e = (double)xv.w - (double)ev.w; s += e * e;
                }
                if (s < dmin) { dmin = s; kmin = k; }
            }
            #pragma unroll
            for (int m = 1; m < 64; m <<= 1) {
                double od = __shfl_xor(dmin, m);
                int   ok = __shfl_xor(kmin, m);
                if (od < dmin || (od == dmin && ok < kmin)) { dmin = od; kmin = ok; }
            }
            if ((lane & 15) == nl) {
                bk[j] = kmin;
                best[j] = (float)dmin - xnorm[j];
            }
        }
    }

    // ---- write quantized rows: lane -> (n = lane>>2, 64B slice = lane&3) ----
    #pragma unroll
    for (int j = 0; j < 4; ++j) {
        int bkn = __shfl(bk[j], lane >> 2);
        const float4* er = (const float4*)(et + (size_t)bkn * DDIM + (lane & 3) * 16);
        float4* op = (float4*)(out + (size_t)(nbase + j * 16 + (lane >> 2)) * DDIM
                                   + (lane & 3) * 16);
        op[0] = er[0]; op[1] = er[1]; op[2] = er[2]; op[3] = er[3];
    }

    // ---- loss partial + completion-counter finalize ----
    float ls = 0.f;
    if (lane < 16) {
        #pragma unroll
        for (int j = 0; j < 4; ++j) ls += fmaxf(xnorm[j] + best[j], 0.f);
    }
    #pragma unroll
    for (int m = 1; m < 64; m <<= 1) ls += __shfl_xor(ls, m);
    if (lane == 0) atomicAdd(loss_accum, ls);

    __syncthreads();   // all 4 waves' atomicAdds issued (program order per wave)
    if (threadIdx.x == 0) {
        __threadfence();
        unsigned old = atomicAdd(counter, 1u);
        if (old == NBLOCKS - 1) {
            __threadfence();
            float total = atomicAdd(loss_accum, 0.f);  // coherent read
            out[(size_t)NVEC * DDIM] = 1.25f * total / 16777216.f;
        }
    }
}

// ---------------- legacy fallback if ws too small ----------------
__global__ __launch_bounds__(512) void vq_prep1_legacy(const float* __restrict__ emb,
                                                       float* __restrict__ wsf) {
    int k = threadIdx.x;
    float s = 0.f;
    float* et = wsf + WS_ET;
    #pragma unroll
    for (int d = 0; d < DDIM; ++d) {
        float e = emb[d * KCB + k];
        s += e * e;
        et[k * DDIM + d] = e;
    }
    wsf[WS_CNORM + k] = s;
    if (k == 0) wsf[WS_LOSS] = 0.f;
}

__global__ __launch_bounds__(256) void vq_main_legacy(const float* __restrict__ x,
                                                      const float* __restrict__ wsf,
                                                      float* __restrict__ out,
                                                      float* __restrict__ loss_accum) {
    const int n = blockIdx.x * 256 + threadIdx.x;
    const float* __restrict__ cnorm = wsf + WS_CNORM;
    const float* __restrict__ et    = wsf + WS_ET;
    float xr[DDIM];
    {
        const float4* xp = (const float4*)(x + (size_t)n * DDIM);
        #pragma unroll
        for (int d4 = 0; d4 < DDIM / 4; ++d4) {
            float4 v = xp[d4];
            xr[4 * d4 + 0] = v.x; xr[4 * d4 + 1] = v.y;
            xr[4 * d4 + 2] = v.z; xr[4 * d4 + 3] = v.w;
        }
    }
    float best = 3.4e38f, second = 3.4e38f;
    int bestk = 0;
    for (int k0 = 0; k0 < KCB; k0 += 8) {
        float acc[8];
        #pragma unroll
        for (int j = 0; j < 8; ++j) {
            const float* ek = et + (k0 + j) * DDIM;
            float s = 0.f;
            #pragma unroll
            for (int d = 0; d < DDIM; ++d) s += xr[d] * ek[d];
            acc[j] = s;
        }
        #pragma unroll
        for (int j = 0; j < 8; ++j) {
            float dist = cnorm[k0 + j] - 2.f * acc[j];
            if (dist < best) { second = best; best = dist; bestk = k0 + j; }
            else if (dist < second) { second = dist; }
        }
    }
    if (second - best < TIE_TH) {
        double bestd = 1e300;
        int bkk = 0;
        for (int k = 0; k < KCB; ++k) {
            const float* ek = et + k * DDIM;
            double s = 0.0;
            #pragma unroll
            for (int d = 0; d < DDIM; ++d) {
                double diff = (double)xr[d] - (double)ek[d];
                s += diff * diff;
            }
            if (s < bestd) { bestd = s; bkk = k; }
        }
        bestk = bkk;
    }
    float sq = 0.f;
    {
        const float4* qp = (const float4*)(et + bestk * DDIM);
        float4* op = (float4*)(out + (size_t)n * DDIM);
        #pragma unroll
        for (int d4 = 0; d4 < DDIM / 4; ++d4) {
            float4 q = qp[d4];
            op[d4] = q;
            float a = q.x - xr[4 * d4 + 0];
            float b = q.y - xr[4 * d4 + 1];
            float c = q.z - xr[4 * d4 + 2];
            float e = q.w - xr[4 * d4 + 3];
            sq += a * a + b * b + c * c + e * e;
        }
    }
    #pragma unroll
    for (int off = 32; off > 0; off >>= 1) sq += __shfl_down(sq, off);
    __shared__ float red[4];
    const int lane = threadIdx.x & 63;
    const int wid  = threadIdx.x >> 6;
    if (lane == 0) red[wid] = sq;
    __syncthreads();
    if (threadIdx.x == 0) atomicAdd(loss_accum, red[0] + red[1] + red[2] + red[3]);
}

__global__ void vq_final(const float* __restrict__ loss_accum,
                         float* __restrict__ out) {
    out[(size_t)NVEC * DDIM] = 1.25f * loss_accum[0] / 16777216.f;
}

extern "C" void kernel_launch(void* const* d_in, const int* in_sizes, int n_in,
                              void* d_out, int out_size, void* d_ws, size_t ws_size,
                              hipStream_t stream) {
    const float* x   = (const float*)d_in[0];
    const float* emb = (const float*)d_in[1];
    float* out = (float*)d_out;
    float* wsf = (float*)d_ws;

    if (ws_size >= (size_t)WS_END * 4) {
        vq_prep<<<9, 512, 0, stream>>>(emb, wsf);
        vq_main_mfma<<<NBLOCKS, 256, 0, stream>>>(x, wsf, out);
    } else {
        vq_prep1_legacy<<<1, 512, 0, stream>>>(emb, wsf);
        vq_main_legacy<<<NVEC / 256, 256, 0, stream>>>(x, wsf, out, wsf + WS_LOSS);
        vq_final<<<1, 1, 0, stream>>>(wsf + WS_LOSS, out);
    }
}

// Round 9
// 245.656 us; speedup vs baseline: 1.1159x; 1.1159x over previous
//
#include <hip/hip_runtime.h>

// VectorQuantizer MI355X (gfx950) — round 9 (= round-8 kernel, resubmitted after
// container failure; never executed)
// R5/R7 post-mortem: TWO independent LDS-staging implementations failed
// correctness (absmax ~0.99) with no counters to debug; abandoned that line.
// Back to the VALIDATED R2 datapath (direct global fragment loads, passed at
// 139us main). Single change: j = 4 -> 8 n-tiles per wave (128 vectors/wave).
//   - per t-iter: same 5 loads, 2x MFMA (48), 2x independent j-chains (ILP)
//   - per vector: fragment-load traffic halved
//   - waves halve to 2048 -> 2 waves/SIMD; __launch_bounds__(256,2) gives the
//     allocator a 256-VGPR budget (est ~210 used, no spill)
// Numerics identical to R2/R3 (3-term bf16 split, TIE_TH=1e-3, fp64 rescan).

#define NVEC 262144
#define DDIM 64
#define KCB  512
#define TIE_TH 1e-3f
#define NTILE 8                          // n-tiles (of 16 vectors) per wave
#define VPB   (4 * NTILE * 16)           // vectors per block = 512
#define NBLOCKS (NVEC / VPB)             // 512

// ws layout (4-byte units)
#define WS_LOSS  0
#define WS_COUNT 1
#define WS_CNORM 64                      // 512 floats
#define WS_ET    1024                    // 512*64 floats (code-major codebook)
#define WS_EH    (WS_ET + KCB * DDIM)    // 4096 uint4
#define WS_EL    (WS_EH + 32 * 2 * 64 * 4)
#define WS_END   (WS_EL + 32 * 2 * 64 * 4)

typedef __attribute__((ext_vector_type(8))) short bf16x8;
typedef __attribute__((ext_vector_type(4))) float f32x4;

static __device__ __forceinline__ unsigned short f2bf_rne(float f) {
    unsigned u = __float_as_uint(f);
    unsigned r = (u + 0x7FFFu + ((u >> 16) & 1u)) >> 16;
    return (unsigned short)r;
}
static __device__ __forceinline__ float bf2f(unsigned short h) {
    return __uint_as_float(((unsigned)h) << 16);
}

// ---------------- merged prep: 9 blocks x 512 (validated in R3) ----------------
__global__ __launch_bounds__(512) void vq_prep(const float* __restrict__ emb,
                                               float* __restrict__ wsf) {
    if (blockIdx.x == 8) {
        int k = threadIdx.x;
        float s = 0.f;
        float* et = wsf + WS_ET;
        #pragma unroll
        for (int d = 0; d < DDIM; ++d) {
            float e = emb[d * KCB + k];
            s += e * e;
            et[k * DDIM + d] = e;
        }
        wsf[WS_CNORM + k] = s;
        if (k == 0) {
            wsf[WS_LOSS] = 0.f;
            ((unsigned*)wsf)[WS_COUNT] = 0u;
        }
        return;
    }
    int tid = blockIdx.x * 512 + threadIdx.x;   // 0..4095
    int l = tid & 63;
    int c = (tid >> 6) & 1;
    int t = tid >> 7;
    int m = t * 16 + (l & 15);
    int dbase = c * 32 + ((l >> 4) & 3) * 8;
    unsigned hh[4], ll[4];
    #pragma unroll
    for (int j2 = 0; j2 < 4; ++j2) {
        float f0 = emb[(dbase + 2 * j2 + 0) * KCB + m];
        float f1 = emb[(dbase + 2 * j2 + 1) * KCB + m];
        unsigned short h0 = f2bf_rne(f0), h1 = f2bf_rne(f1);
        unsigned short l0 = f2bf_rne(f0 - bf2f(h0)), l1 = f2bf_rne(f1 - bf2f(h1));
        hh[j2] = (unsigned)h0 | ((unsigned)h1 << 16);
        ll[j2] = (unsigned)l0 | ((unsigned)l1 << 16);
    }
    uint4* ehp = (uint4*)(wsf + WS_EH);
    uint4* elp = (uint4*)(wsf + WS_EL);
    ehp[tid] = make_uint4(hh[0], hh[1], hh[2], hh[3]);
    elp[tid] = make_uint4(ll[0], ll[1], ll[2], ll[3]);
}

// ---------------- main: one wave = 128 vectors vs all 512 codes ----------------
__global__ __launch_bounds__(256, 2) void vq_main_mfma(const float* __restrict__ x,
                                                       float* __restrict__ wsf,
                                                       float* __restrict__ out) {
    const int lane = threadIdx.x & 63;
    const int quad = lane >> 4;
    const int nbase = (blockIdx.x * 4 + (threadIdx.x >> 6)) * (NTILE * 16);

    const float* __restrict__ cnorm = wsf + WS_CNORM;
    const float* __restrict__ et    = wsf + WS_ET;
    const bf16x8* __restrict__ ehp  = (const bf16x8*)(wsf + WS_EH);
    const bf16x8* __restrict__ elp  = (const bf16x8*)(wsf + WS_EL);
    float* loss_accum = wsf + WS_LOSS;
    unsigned* counter = (unsigned*)wsf + WS_COUNT;

    // ---- load x tile, build B-fragments (hi/lo), accumulate ||x||^2 ----
    bf16x8 xh[NTILE][2], xl[NTILE][2];
    float xnorm[NTILE];
    #pragma unroll
    for (int j = 0; j < NTILE; ++j) {
        float s = 0.f;
        #pragma unroll
        for (int c = 0; c < 2; ++c) {
            const float* xrow = x + (size_t)(nbase + j * 16 + (lane & 15)) * DDIM
                                  + c * 32 + quad * 8;
            float4 xa = *(const float4*)xrow;
            float4 xb = *(const float4*)(xrow + 4);
            s += xa.x * xa.x + xa.y * xa.y + xa.z * xa.z + xa.w * xa.w;
            s += xb.x * xb.x + xb.y * xb.y + xb.z * xb.z + xb.w * xb.w;
            float f[8] = {xa.x, xa.y, xa.z, xa.w, xb.x, xb.y, xb.z, xb.w};
            union { bf16x8 v; unsigned short u[8]; } H, L;
            #pragma unroll
            for (int e = 0; e < 8; ++e) {
                unsigned short h = f2bf_rne(f[e]);
                H.u[e] = h;
                L.u[e] = f2bf_rne(f[e] - bf2f(h));
            }
            xh[j][c] = H.v;
            xl[j][c] = L.v;
        }
        s += __shfl_xor(s, 16);
        s += __shfl_xor(s, 32);
        xnorm[j] = s;
    }

    // ---- argmin over 32 code-tiles (R2 form: direct loads, no rotation) ----
    float best[NTILE], second[NTILE];
    int bestv[NTILE];
    #pragma unroll
    for (int j = 0; j < NTILE; ++j) { best[j] = 3.4e38f; second[j] = 3.4e38f; bestv[j] = 0; }

    for (int t = 0; t < 32; ++t) {
        bf16x8 eh0 = ehp[(t * 2 + 0) * 64 + lane];
        bf16x8 eh1 = ehp[(t * 2 + 1) * 64 + lane];
        bf16x8 el0 = elp[(t * 2 + 0) * 64 + lane];
        bf16x8 el1 = elp[(t * 2 + 1) * 64 + lane];
        float4 cn = *(const float4*)(cnorm + t * 16 + quad * 4);
        const int kb = t * 16;
        #pragma unroll
        for (int j = 0; j < NTILE; ++j) {
            f32x4 acc = {0.f, 0.f, 0.f, 0.f};
            acc = __builtin_amdgcn_mfma_f32_16x16x32_bf16(eh0, xh[j][0], acc, 0, 0, 0);
            acc = __builtin_amdgcn_mfma_f32_16x16x32_bf16(eh1, xh[j][1], acc, 0, 0, 0);
            acc = __builtin_amdgcn_mfma_f32_16x16x32_bf16(el0, xh[j][0], acc, 0, 0, 0);
            acc = __builtin_amdgcn_mfma_f32_16x16x32_bf16(el1, xh[j][1], acc, 0, 0, 0);
            acc = __builtin_amdgcn_mfma_f32_16x16x32_bf16(eh0, xl[j][0], acc, 0, 0, 0);
            acc = __builtin_amdgcn_mfma_f32_16x16x32_bf16(eh1, xl[j][1], acc, 0, 0, 0);
            float cns[4] = {cn.x, cn.y, cn.z, cn.w};
            #pragma unroll
            for (int r = 0; r < 4; ++r) {
                float dist = __builtin_fmaf(-2.f, acc[r], cns[r]);
                bool lt = dist < best[j];
                second[j] = fminf(second[j], fmaxf(dist, best[j]));
                bestv[j] = lt ? (kb + r) : bestv[j];
                best[j] = fminf(best[j], dist);
            }
        }
    }

    // ---- reduce across the 4 quads ----
    int bk[NTILE];
    #pragma unroll
    for (int j = 0; j < NTILE; ++j) bk[j] = bestv[j] + quad * 4;
    #pragma unroll
    for (int j = 0; j < NTILE; ++j) {
        #pragma unroll
        for (int m = 16; m <= 32; m <<= 1) {
            float ob = __shfl_xor(best[j], m);
            float os = __shfl_xor(second[j], m);
            int   ok = __shfl_xor(bk[j], m);
            float nb = fminf(best[j], ob);
            float ns = fminf(fminf(second[j], os), fmaxf(best[j], ob));
            bool take = (ob < best[j]) || (ob == best[j] && ok < bk[j]);
            bk[j] = take ? ok : bk[j];
            best[j] = nb;
            second[j] = ns;
        }
    }

    // ---- near-tie: whole-wave cooperative exact fp64 rescan (rare) ----
    #pragma unroll
    for (int j = 0; j < NTILE; ++j) {
        unsigned long long need = __ballot(second[j] - best[j] < TIE_TH) & 0xFFFFULL;
        while (need) {
            int nl = __ffsll(need) - 1;
            need &= need - 1;
            const float* xr = x + (size_t)(nbase + j * 16 + nl) * DDIM;
            double dmin = 1e300;
            int kmin = 0;
            #pragma unroll
            for (int i = 0; i < 8; ++i) {
                int k = lane * 8 + i;
                const float* er = et + k * DDIM;
                double s = 0.0;
                for (int d4 = 0; d4 < 16; ++d4) {
                    float4 xv = *(const float4*)(xr + d4 * 4);
                    float4 ev = *(const float4*)(er + d4 * 4);
                    double a = (double)xv.x - (double)ev.x; s += a * a;
                    double b = (double)xv.y - (double)ev.y; s += b * b;
                    double c = (double)xv.z - (double)ev.z; s += c * c;
                    double e = (double)xv.w - (double)ev.w; s += e * e;
                }
                if (s < dmin) { dmin = s; kmin = k; }
            }
            #pragma unroll
            for (int m = 1; m < 64; m <<= 1) {
                double od = __shfl_xor(dmin, m);
                int   ok = __shfl_xor(kmin, m);
                if (od < dmin || (od == dmin && ok < kmin)) { dmin = od; kmin = ok; }
            }
            if ((lane & 15) == nl) {
                bk[j] = kmin;
                best[j] = (float)dmin - xnorm[j];
            }
        }
    }

    // ---- write quantized rows: lane -> (n = lane>>2, 64B slice = lane&3) ----
    #pragma unroll
    for (int j = 0; j < NTILE; ++j) {
        int bkn = __shfl(bk[j], lane >> 2);
        const float4* er = (const float4*)(et + (size_t)bkn * DDIM + (lane & 3) * 16);
        float4* op = (float4*)(out + (size_t)(nbase + j * 16 + (lane >> 2)) * DDIM
                                   + (lane & 3) * 16);
        op[0] = er[0]; op[1] = er[1]; op[2] = er[2]; op[3] = er[3];
    }

    // ---- loss partial + completion-counter finalize (validated in R3) ----
    float ls = 0.f;
    if (lane < 16) {
        #pragma unroll
        for (int j = 0; j < NTILE; ++j) ls += fmaxf(xnorm[j] + best[j], 0.f);
    }
    #pragma unroll
    for (int m = 1; m < 64; m <<= 1) ls += __shfl_xor(ls, m);
    if (lane == 0) atomicAdd(loss_accum, ls);

    __syncthreads();
    if (threadIdx.x == 0) {
        __threadfence();
        unsigned old = atomicAdd(counter, 1u);
        if (old == NBLOCKS - 1) {
            __threadfence();
            float total = atomicAdd(loss_accum, 0.f);
            out[(size_t)NVEC * DDIM] = 1.25f * total / 16777216.f;
        }
    }
}

// ---------------- legacy fallback if ws too small ----------------
__global__ __launch_bounds__(512) void vq_prep1_legacy(const float* __restrict__ emb,
                                                       float* __restrict__ wsf) {
    int k = threadIdx.x;
    float s = 0.f;
    float* et = wsf + WS_ET;
    #pragma unroll
    for (int d = 0; d < DDIM; ++d) {
        float e = emb[d * KCB + k];
        s += e * e;
        et[k * DDIM + d] = e;
    }
    wsf[WS_CNORM + k] = s;
    if (k == 0) wsf[WS_LOSS] = 0.f;
}

__global__ __launch_bounds__(256) void vq_main_legacy(const float* __restrict__ x,
                                                      const float* __restrict__ wsf,
                                                      float* __restrict__ out,
                                                      float* __restrict__ loss_accum) {
    const int n = blockIdx.x * 256 + threadIdx.x;
    const float* __restrict__ cnorm = wsf + WS_CNORM;
    const float* __restrict__ et    = wsf + WS_ET;
    float xr[DDIM];
    {
        const float4* xp = (const float4*)(x + (size_t)n * DDIM);
        #pragma unroll
        for (int d4 = 0; d4 < DDIM / 4; ++d4) {
            float4 v = xp[d4];
            xr[4 * d4 + 0] = v.x; xr[4 * d4 + 1] = v.y;
            xr[4 * d4 + 2] = v.z; xr[4 * d4 + 3] = v.w;
        }
    }
    float best = 3.4e38f, second = 3.4e38f;
    int bestk = 0;
    for (int k0 = 0; k0 < KCB; k0 += 8) {
        float acc[8];
        #pragma unroll
        for (int j = 0; j < 8; ++j) {
            const float* ek = et + (k0 + j) * DDIM;
            float s = 0.f;
            #pragma unroll
            for (int d = 0; d < DDIM; ++d) s += xr[d] * ek[d];
            acc[j] = s;
        }
        #pragma unroll
        for (int j = 0; j < 8; ++j) {
            float dist = cnorm[k0 + j] - 2.f * acc[j];
            if (dist < best) { second = best; best = dist; bestk = k0 + j; }
            else if (dist < second) { second = dist; }
        }
    }
    if (second - best < TIE_TH) {
        double bestd = 1e300;
        int bkk = 0;
        for (int k = 0; k < KCB; ++k) {
            const float* ek = et + k * DDIM;
            double s = 0.0;
            #pragma unroll
            for (int d = 0; d < DDIM; ++d) {
                double diff = (double)xr[d] - (double)ek[d];
                s += diff * diff;
            }
            if (s < bestd) { bestd = s; bkk = k; }
        }
        bestk = bkk;
    }
    float sq = 0.f;
    {
        const float4* qp = (const float4*)(et + bestk * DDIM);
        float4* op = (float4*)(out + (size_t)n * DDIM);
        #pragma unroll
        for (int d4 = 0; d4 < DDIM / 4; ++d4) {
            float4 q = qp[d4];
            op[d4] = q;
            float a = q.x - xr[4 * d4 + 0];
            float b = q.y - xr[4 * d4 + 1];
            float c = q.z - xr[4 * d4 + 2];
            float e = q.w - xr[4 * d4 + 3];
            sq += a * a + b * b + c * c + e * e;
        }
    }
    #pragma unroll
    for (int off = 32; off > 0; off >>= 1) sq += __shfl_down(sq, off);
    __shared__ float red[4];
    const int lane = threadIdx.x & 63;
    const int wid  = threadIdx.x >> 6;
    if (lane == 0) red[wid] = sq;
    __syncthreads();
    if (threadIdx.x == 0) atomicAdd(loss_accum, red[0] + red[1] + red[2] + red[3]);
}

__global__ void vq_final(const float* __restrict__ loss_accum,
                         float* __restrict__ out) {
    out[(size_t)NVEC * DDIM] = 1.25f * loss_accum[0] / 16777216.f;
}

extern "C" void kernel_launch(void* const* d_in, const int* in_sizes, int n_in,
                              void* d_out, int out_size, void* d_ws, size_t ws_size,
                              hipStream_t stream) {
    const float* x   = (const float*)d_in[0];
    const float* emb = (const float*)d_in[1];
    float* out = (float*)d_out;
    float* wsf = (float*)d_ws;

    if (ws_size >= (size_t)WS_END * 4) {
        vq_prep<<<9, 512, 0, stream>>>(emb, wsf);
        vq_main_mfma<<<NBLOCKS, 256, 0, stream>>>(x, wsf, out);
    } else {
        vq_prep1_legacy<<<1, 512, 0, stream>>>(emb, wsf);
        vq_main_legacy<<<NVEC / 256, 256, 0, stream>>>(x, wsf, out, wsf + WS_LOSS);
        vq_final<<<1, 1, 0, stream>>>(wsf + WS_LOSS, out);
    }
}